// Round 10
// baseline (341.284 us; speedup 1.0000x reference)
//
#include <hip/hip_runtime.h>

#define N_NODES 50000
#define N_EDGES 800000
#define HD 128
#define NGRAPH 64
#define NOUT 8
#define SLOTS 64
#define GAGRID 3125  /* 50000/16 exact */
#define EPB 2048     /* edges per chunk in fillx */
#define WG_NB 256    /* wgemm blocks */
#define WG_RPB 196   /* rows per wgemm block: 256*196 >= 50000 */

typedef __attribute__((ext_vector_type(8))) short bf8_t;
typedef __attribute__((ext_vector_type(4))) float f4_t;
typedef __attribute__((ext_vector_type(2))) float f2_t;
typedef __attribute__((ext_vector_type(8))) unsigned short us8;

__device__ __forceinline__ unsigned short f2b(float f) {   // fp32 -> bf16 RNE
    unsigned u = __float_as_uint(f);
    u += 0x7fffu + ((u >> 16) & 1u);
    return (unsigned short)(u >> 16);
}
__device__ __forceinline__ float b2f(unsigned short h) {
    return __uint_as_float(((unsigned)h) << 16);
}

// ---- packed bf16-row accumulate ----
__device__ __forceinline__ void acc_row(f2_t a2[4], us8 v) {
    union { us8 s; uint4 u; } cv; cv.s = v;
    unsigned uw[4] = {cv.u.x, cv.u.y, cv.u.z, cv.u.w};
#pragma unroll
    for (int p = 0; p < 4; ++p) {
        f2_t t;
        t.x = __uint_as_float(uw[p] << 16);
        t.y = __uint_as_float(uw[p] & 0xffff0000u);
        a2[p] += t;
    }
}
__device__ __forceinline__ void acc_row_m(f2_t a2[4], us8 v, float m) {
    union { us8 s; uint4 u; } cv; cv.s = v;
    unsigned uw[4] = {cv.u.x, cv.u.y, cv.u.z, cv.u.w};
#pragma unroll
    for (int p = 0; p < 4; ++p) {
        f2_t t;
        t.x = __uint_as_float(uw[p] << 16);
        t.y = __uint_as_float(uw[p] & 0xffff0000u);
        a2[p].x = fmaf(m, t.x, a2[p].x);
        a2[p].y = fmaf(m, t.y, a2[p].y);
    }
}

// ---------------- convert W (3 mats) + zero degc / Wacc / outacc8 / cnt ----------------
__global__ __launch_bounds__(256) void cvtw_k(const float* __restrict__ W0,
                                              const float* __restrict__ W1,
                                              const float* __restrict__ W2,
                                              unsigned short* __restrict__ WT,
                                              int* __restrict__ degc,
                                              float* __restrict__ Wacc,
                                              float* __restrict__ outacc8,
                                              float* __restrict__ cnt) {
    const int idx = blockIdx.x * 256 + threadIdx.x;
    const int stride = gridDim.x * 256;
    if (idx < 3 * HD * HD) {
        int w = idx >> 14;
        int rem = idx & 16383;
        int n = rem >> 7;
        int k = rem & 127;
        const float* W = (w == 0) ? W0 : (w == 1) ? W1 : W2;
        WT[(size_t)w * HD * HD + n * HD + k] = f2b(W[k * HD + n]);
    }
    if (idx < N_NODES) degc[idx] = 0;
    // zero Wacc: 50000*64 f32 = 800000 float4
    float4* W4 = (float4*)Wacc;
    for (int z = idx; z < N_NODES * 16; z += stride)
        W4[z] = (float4){0.f, 0.f, 0.f, 0.f};
    if (idx < 8 * NGRAPH * NOUT * 8) { /* 8*512 */ }
    if (idx < 8 * 512) outacc8[idx] = 0.f;
    if (idx < NGRAPH) cnt[idx] = 0.f;
}

// ---------------- XCD-partitioned CSR build (proven round 4) ----------------
__global__ __launch_bounds__(256) void fillx_k(const int* __restrict__ src,
                                               const int* __restrict__ dst,
                                               int* __restrict__ degc,
                                               unsigned short* __restrict__ slots) {
    const int p = blockIdx.x & 7;
    const int c = blockIdx.x >> 3;
    const int e0 = c * EPB;
    int e1 = e0 + EPB; if (e1 > N_EDGES) e1 = N_EDGES;
    for (int e = e0 + threadIdx.x; e < e1; e += 256) {
        int d = dst[e];
        if (((d >> 4) & 7) == p) {
            int s = src[e];
            int pos = atomicAdd(&degc[d], 1);
            if (pos < SLOTS)
                slots[(size_t)d * SLOTS + pos] = (unsigned short)s;
        }
    }
}

// ---------------- layer-0 MFMA matmul (fp32 in, bf16 out, *dinv epilogue) ----------------
__global__ __launch_bounds__(256) void mm_f32in_k(const float* __restrict__ X,
                                                  const unsigned short* __restrict__ WT,
                                                  const int* __restrict__ degc,
                                                  unsigned short* __restrict__ Y) {
    const int lane = threadIdx.x & 63;
    const int wave = threadIdx.x >> 6;
    const int r = lane & 15;
    const int q = lane >> 4;
    const int row0 = blockIdx.x * 64 + wave * 16;
    int arow = row0 + r; if (arow >= N_NODES) arow = N_NODES - 1;

    f4_t acc[8];
#pragma unroll
    for (int n = 0; n < 8; ++n) acc[n] = (f4_t){0.f, 0.f, 0.f, 0.f};

#pragma unroll
    for (int kb = 0; kb < 4; ++kb) {
        f4_t fa = __builtin_nontemporal_load((const f4_t*)(X + (size_t)arow * HD + kb * 32 + q * 8));
        f4_t fb = __builtin_nontemporal_load((const f4_t*)(X + (size_t)arow * HD + kb * 32 + q * 8 + 4));
        bf8_t a;
        a[0] = (short)f2b(fa[0]); a[1] = (short)f2b(fa[1]);
        a[2] = (short)f2b(fa[2]); a[3] = (short)f2b(fa[3]);
        a[4] = (short)f2b(fb[0]); a[5] = (short)f2b(fb[1]);
        a[6] = (short)f2b(fb[2]); a[7] = (short)f2b(fb[3]);
#pragma unroll
        for (int n = 0; n < 8; ++n) {
            bf8_t b = *(const bf8_t*)(WT + (size_t)(n * 16 + r) * HD + kb * 32 + q * 8);
            acc[n] = __builtin_amdgcn_mfma_f32_16x16x32_bf16(a, b, acc[n], 0, 0, 0);
        }
    }
    const int orow = row0 + q * 4;
#pragma unroll
    for (int i = 0; i < 4; ++i) {
        int rr = orow + i;
        if (rr < N_NODES) {
            float dv = rsqrtf((float)degc[rr] + 1.0f);
#pragma unroll
            for (int n = 0; n < 8; ++n)
                Y[(size_t)rr * HD + n * 16 + r] = f2b(acc[n][i] * dv);
        }
    }
}

// ---------------- fused gather+mm (unchanged from round 9) ----------------
__global__ __launch_bounds__(256, 4) void fusedGM2_k(const unsigned short* __restrict__ T,
                                                     const int* __restrict__ degc,
                                                     const unsigned short* __restrict__ slots,
                                                     const float* __restrict__ bias,
                                                     const unsigned short* __restrict__ WT,
                                                     unsigned short* __restrict__ Y) {
    __shared__ unsigned short hs[16][136];
    const int tid = threadIdx.x;
    const int base = blockIdx.x * 16;

    {
        const int g = tid >> 4;
        const int l = tid & 15;
        const int j8 = l * 8;
        const int i = base + g;
        const int dg = degc[i];
        int dc = dg; if (dc > SLOTS) dc = SLOTS;
        const float di = rsqrtf((float)dg + 1.0f);
        const unsigned short* sl = slots + (size_t)i * SLOTS;

        f2_t a2[4];
#pragma unroll
        for (int p = 0; p < 4; ++p) a2[p] = (f2_t){0.f, 0.f};
        int e = 0;
        for (; e + 15 < dc; e += 16) {
            us8 i0 = *(const us8*)(sl + e);
            us8 i1 = *(const us8*)(sl + e + 8);
            us8 v[16];
#pragma unroll
            for (int u = 0; u < 8; ++u) v[u]     = *(const us8*)(T + (size_t)i0[u] * HD + j8);
#pragma unroll
            for (int u = 0; u < 8; ++u) v[u + 8] = *(const us8*)(T + (size_t)i1[u] * HD + j8);
#pragma unroll
            for (int u = 0; u < 16; ++u) acc_row(a2, v[u]);
        }
        if (e < dc) {
            us8 i0 = *(const us8*)(sl + e);
            us8 i1 = *(const us8*)(sl + e + 8);
            const unsigned short safe = i0[0];
            int s[16]; float m[16];
#pragma unroll
            for (int u = 0; u < 8; ++u) {
                m[u] = (e + u < dc) ? 1.f : 0.f;
                s[u] = (e + u < dc) ? i0[u] : safe;
            }
#pragma unroll
            for (int u = 0; u < 8; ++u) {
                m[u + 8] = (e + 8 + u < dc) ? 1.f : 0.f;
                s[u + 8] = (e + 8 + u < dc) ? i1[u] : safe;
            }
            us8 v[16];
#pragma unroll
            for (int u = 0; u < 16; ++u) v[u] = *(const us8*)(T + (size_t)s[u] * HD + j8);
#pragma unroll
            for (int u = 0; u < 16; ++u) acc_row_m(a2, v[u], m[u]);
        }
        float a[8];
#pragma unroll
        for (int p = 0; p < 4; ++p) { a[2 * p] = a2[p].x; a[2 * p + 1] = a2[p].y; }
        us8 tv = *(const us8*)(T + (size_t)i * HD + j8);
        float4 bv0 = *(const float4*)(bias + j8);
        float4 bv1 = *(const float4*)(bias + j8 + 4);
        float bb[8] = {bv0.x, bv0.y, bv0.z, bv0.w, bv1.x, bv1.y, bv1.z, bv1.w};
        us8 o;
#pragma unroll
        for (int k = 0; k < 8; ++k) {
            float r = di * (a[k] + b2f(tv[k])) + bb[k];
            r = fmaxf(r, 0.f);
            o[k] = f2b(r);
        }
        *(us8*)(&hs[g][j8]) = o;
    }
    __syncthreads();

    {
        const int lane = tid & 63;
        const int wave = tid >> 6;
        const int r = lane & 15;
        const int q = lane >> 4;
        const int n0 = wave * 2;

        f4_t acc0 = (f4_t){0.f, 0.f, 0.f, 0.f};
        f4_t acc1 = (f4_t){0.f, 0.f, 0.f, 0.f};
#pragma unroll
        for (int kb = 0; kb < 4; ++kb) {
            bf8_t a = *(const bf8_t*)(&hs[r][kb * 32 + q * 8]);
            bf8_t b0 = *(const bf8_t*)(WT + (size_t)(n0 * 16 + r) * HD + kb * 32 + q * 8);
            bf8_t b1 = *(const bf8_t*)(WT + (size_t)(n0 * 16 + 16 + r) * HD + kb * 32 + q * 8);
            acc0 = __builtin_amdgcn_mfma_f32_16x16x32_bf16(a, b0, acc0, 0, 0, 0);
            acc1 = __builtin_amdgcn_mfma_f32_16x16x32_bf16(a, b1, acc1, 0, 0, 0);
        }
#pragma unroll
        for (int i = 0; i < 4; ++i) {
            int rr = base + q * 4 + i;
            float dv = rsqrtf((float)degc[rr] + 1.0f);
            Y[(size_t)rr * HD + n0 * 16 + r]      = f2b(acc0[i] * dv);
            Y[(size_t)rr * HD + n0 * 16 + 16 + r] = f2b(acc1[i] * dv);
        }
    }
}

// ---------------- W-build: w[j,g] = sum di[dst in g] over edges j->dst (+self) ----------------
// XCD-partitioned by SOURCE row j (same trick as fillx): block p only issues atomics
// to rows with ((j>>4)&7)==p, so each 256B W row lives on one XCD's L2 -> no
// cross-XCD dirty-line migration. Slot lists re-scanned 8x (sequential, L1/L3-cheap).
// cnt computed by p==0 blocks via LDS histogram (196*64 = 12.5K global atomics).
__global__ __launch_bounds__(256) void wbuildx_k(const int* __restrict__ degc,
                                                 const unsigned short* __restrict__ slots,
                                                 const int* __restrict__ batch,
                                                 float* __restrict__ W,
                                                 float* __restrict__ cnt) {
    __shared__ int hist[64];
    const int p = blockIdx.x & 7;
    const int chunk = blockIdx.x >> 3;
    const int i = chunk * 256 + (int)threadIdx.x;
    const bool doCnt = (p == 0);
    if (doCnt && threadIdx.x < 64) hist[threadIdx.x] = 0;
    if (doCnt) __syncthreads();
    if (i < N_NODES) {
        const int dg = degc[i];
        int dc = dg; if (dc > SLOTS) dc = SLOTS;
        const float di = rsqrtf((float)dg + 1.0f);
        const int g = batch[i];
        const unsigned short* sl = slots + (size_t)i * SLOTS;
        for (int s = 0; s < dc; ++s) {
            int j = sl[s];
            if (((j >> 4) & 7) == p)
                atomicAdd(&W[(size_t)j * NGRAPH + g], di);
        }
        if (((i >> 4) & 7) == p)
            atomicAdd(&W[(size_t)i * NGRAPH + g], di);   // self-loop term
        if (doCnt) atomicAdd(&hist[g], 1);
    }
    if (doCnt) {
        __syncthreads();
        if (threadIdx.x < 64 && hist[threadIdx.x] > 0)
            atomicAdd(&cnt[threadIdx.x], (float)hist[threadIdx.x]);
    }
}

// ---------------- streaming weighted pool-GEMM: outacc8 += (W'^T @ T3) @ Wh ----------------
// Block b owns rows [b*196, +196): stages W/T3 tiles in LDS, accumulates 64x128
// partial (thread = (g, 32-col quad)), folds with Wh to 64x8, LDS-reduces, and
// adds into the per-XCD replica outacc8[b&7] (512 atomics/block, XCD-local).
// Replaces the 205MB random layer-3 gather with 25.6MB streaming.
__global__ __launch_bounds__(256) void wgemm_k(const float* __restrict__ W,
                                               const unsigned short* __restrict__ T3,
                                               const float* __restrict__ Wh,
                                               float* __restrict__ outacc8) {
    __shared__ float Wt[128 * 64];             // 32KB
    __shared__ unsigned short Tt[128 * 128];   // 32KB
    __shared__ float lpo[256][9];              // padded: avoid 16-way bank conflict
    const int tid = threadIdx.x;
    const int b = blockIdx.x;
    const int j0 = b * WG_RPB;
    int j1 = j0 + WG_RPB; if (j1 > N_NODES) j1 = N_NODES;
    const int g = tid >> 2;
    const int c0 = (tid & 3) * 32;

    float acc[32];
#pragma unroll
    for (int k = 0; k < 32; ++k) acc[k] = 0.f;

    for (int jt = j0; jt < j1; jt += 128) {
        int nt = j1 - jt; if (nt > 128) nt = 128;
        for (int idx = tid; idx < nt * 64; idx += 256)
            Wt[idx] = W[(size_t)jt * 64 + idx];
        for (int u = tid; u < nt * 16; u += 256)
            ((us8*)Tt)[u] = ((const us8*)(T3 + (size_t)jt * HD))[u];
        __syncthreads();
        for (int r = 0; r < nt; ++r) {
            float w = Wt[r * 64 + g];
            const unsigned short* trow = &Tt[r * 128 + c0];
#pragma unroll
            for (int u = 0; u < 4; ++u) {
                us8 tv = *(const us8*)(trow + u * 8);
#pragma unroll
                for (int k = 0; k < 8; ++k)
                    acc[u * 8 + k] = fmaf(w, b2f(tv[k]), acc[u * 8 + k]);
            }
        }
        __syncthreads();
    }

    // fold with Wh: po[o] = sum_k acc[k] * Wh[(c0+k), o]
    float po[8];
#pragma unroll
    for (int o = 0; o < 8; ++o) po[o] = 0.f;
#pragma unroll
    for (int k = 0; k < 32; ++k) {
        float a = acc[k];
        const float* wr = Wh + (size_t)(c0 + k) * NOUT;
#pragma unroll
        for (int o = 0; o < 8; ++o) po[o] = fmaf(a, wr[o], po[o]);
    }
#pragma unroll
    for (int o = 0; o < 8; ++o) lpo[tid][o] = po[o];
    __syncthreads();

    // reduce the 4 col-quads per g; 512 outputs; thread handles 2
    const int t2 = tid * 2;
#pragma unroll
    for (int z = 0; z < 2; ++z) {
        int idx = t2 + z;                     // 0..511 = g*8+o
        int gg = idx >> 3, oo = idx & 7;
        float s = lpo[gg * 4 + 0][oo] + lpo[gg * 4 + 1][oo]
                + lpo[gg * 4 + 2][oo] + lpo[gg * 4 + 3][oo];
        atomicAdd(&outacc8[(size_t)(b & 7) * 512 + idx], s);
    }
}

// ---------------- head: reduce 8 XCD replicas, apply /cnt, +b2@Wh, +bh ----------------
__global__ __launch_bounds__(512) void head3_k(const float* __restrict__ outacc8,
                                               const float* __restrict__ cnt,
                                               const float* __restrict__ b2,
                                               const float* __restrict__ Wh,
                                               const float* __restrict__ bh,
                                               float* __restrict__ out) {
    const int t = threadIdx.x;
    const int g = t >> 3, o = t & 7;
    float s = 0.f;
#pragma unroll
    for (int x = 0; x < 8; ++x) s += outacc8[x * 512 + g * 8 + o];
    float cg = cnt[g];
    float r;
    if (cg > 0.f) {
        float bb2 = 0.f;
        for (int c = 0; c < HD; ++c) bb2 += b2[c] * Wh[c * NOUT + o];
        r = bh[o] + s / cg + bb2;
    } else {
        r = bh[o];
    }
    out[g * NOUT + o] = r;
}

extern "C" void kernel_launch(void* const* d_in, const int* in_sizes, int n_in,
                              void* d_out, int out_size, void* d_ws, size_t ws_size,
                              hipStream_t stream) {
    const float* x  = (const float*)d_in[0];
    const int*   ei = (const int*)d_in[1];
    const int*   batch = (const int*)d_in[2];
    const float* W0 = (const float*)d_in[3];
    const float* b0 = (const float*)d_in[4];
    const float* W1 = (const float*)d_in[5];
    const float* b1 = (const float*)d_in[6];
    const float* W2 = (const float*)d_in[7];
    const float* b2 = (const float*)d_in[8];
    const float* Wh = (const float*)d_in[9];
    const float* bh = (const float*)d_in[10];
    float* out = (float*)d_out;

    const int* src = ei;
    const int* dst = ei + N_EDGES;

    char* wsb = (char*)d_ws;
    int*            degc  = (int*)(wsb + 0);                     // N ints (200 KB)
    unsigned short* slots = (unsigned short*)(wsb + 200000);     // N*64 ushort (6.4 MB)
    unsigned short* WT    = (unsigned short*)(wsb + 6600000);    // 3*HD*HD bf16 (98 KB)
    unsigned short* A     = (unsigned short*)(wsb + 6698304);    // N*HD bf16 (12.8 MB)
    unsigned short* C     = (unsigned short*)(wsb + 19498304);   // N*HD bf16 (12.8 MB)
    float*          Wacc  = (float*)(wsb + 33000000);            // N*64 f32 (12.8 MB)
    float*          oacc8 = (float*)(wsb + 46000000);            // 8*512 f32 (16 KB)
    float*          cnt   = (float*)(wsb + 46100000);            // 64 f32

    const int mmGrid    = (N_NODES + 63) / 64;                   // 782
    const int fillxGrid = ((N_EDGES + EPB - 1) / EPB) * 8;       // 391*8 = 3128
    const int wbGrid    = ((N_NODES + 255) / 256) * 8;           // 196*8 = 1568

    // ---- weight convert + zero-init (degc, Wacc, outacc8, cnt) ----
    cvtw_k<<<(N_NODES + 255) / 256, 256, 0, stream>>>(W0, W1, W2, WT, degc, Wacc, oacc8, cnt);

    // ---- XCD-partitioned CSR build ----
    fillx_k<<<fillxGrid, 256, 0, stream>>>(src, dst, degc, slots);

    // ---- layer 0 matmul: x @ W0, *dinv -> A (=T1) ----
    mm_f32in_k<<<mmGrid, 256, 0, stream>>>(x, WT, degc, A);

    // ---- layer 1: gather(T1)+b0+relu -> @W1 -> *dinv -> C (=T2) ----
    fusedGM2_k<<<GAGRID, 256, 0, stream>>>(A, degc, slots, b0, WT + HD * HD, C);

    // ---- layer 2: gather(T2)+b1+relu -> @W2 -> *dinv -> A (=T3) ----
    fusedGM2_k<<<GAGRID, 256, 0, stream>>>(C, degc, slots, b1, WT + 2 * HD * HD, A);

    // ---- layer 3 + pool, linearized: build w[j,g], then streaming GEMM ----
    wbuildx_k<<<wbGrid, 256, 0, stream>>>(degc, slots, batch, Wacc, cnt);
    wgemm_k<<<WG_NB, 256, 0, stream>>>(Wacc, A, Wh, oacc8);
    head3_k<<<1, 512, 0, stream>>>(oacc8, cnt, b2, Wh, bh, out);
}

// Round 11
// 289.927 us; speedup vs baseline: 1.1771x; 1.1771x over previous
//
#include <hip/hip_runtime.h>

#define N_NODES 50000
#define N_EDGES 800000
#define HD 128
#define NGRAPH 64
#define NOUT 8
#define SLOTS 64
#define GAGRID 3125  /* 50000/16 exact */
#define EPB 2048     /* edges per chunk in fillx */

typedef __attribute__((ext_vector_type(8))) short bf8_t;
typedef __attribute__((ext_vector_type(4))) float f4_t;
typedef __attribute__((ext_vector_type(2))) float f2_t;
typedef __attribute__((ext_vector_type(8))) unsigned short us8;

__device__ __forceinline__ unsigned short f2b(float f) {   // fp32 -> bf16 RNE
    unsigned u = __float_as_uint(f);
    u += 0x7fffu + ((u >> 16) & 1u);
    return (unsigned short)(u >> 16);
}
__device__ __forceinline__ float b2f(unsigned short h) {
    return __uint_as_float(((unsigned)h) << 16);
}

// ---- packed bf16-row accumulate ----
__device__ __forceinline__ void acc_row(f2_t a2[4], us8 v) {
    union { us8 s; uint4 u; } cv; cv.s = v;
    unsigned uw[4] = {cv.u.x, cv.u.y, cv.u.z, cv.u.w};
#pragma unroll
    for (int p = 0; p < 4; ++p) {
        f2_t t;
        t.x = __uint_as_float(uw[p] << 16);
        t.y = __uint_as_float(uw[p] & 0xffff0000u);
        a2[p] += t;
    }
}
__device__ __forceinline__ void acc_row_m(f2_t a2[4], us8 v, float m) {
    union { us8 s; uint4 u; } cv; cv.s = v;
    unsigned uw[4] = {cv.u.x, cv.u.y, cv.u.z, cv.u.w};
#pragma unroll
    for (int p = 0; p < 4; ++p) {
        f2_t t;
        t.x = __uint_as_float(uw[p] << 16);
        t.y = __uint_as_float(uw[p] & 0xffff0000u);
        a2[p].x = fmaf(m, t.x, a2[p].x);
        a2[p].y = fmaf(m, t.y, a2[p].y);
    }
}

// ---------------- convert W (3 mats) + zero degc/sums/cnt ----------------
__global__ __launch_bounds__(256) void cvtw_k(const float* __restrict__ W0,
                                              const float* __restrict__ W1,
                                              const float* __restrict__ W2,
                                              unsigned short* __restrict__ WT,
                                              int* __restrict__ degc,
                                              float* __restrict__ sums,
                                              float* __restrict__ cnt) {
    int idx = blockIdx.x * 256 + threadIdx.x;
    if (idx < 3 * HD * HD) {
        int w = idx >> 14;
        int rem = idx & 16383;
        int n = rem >> 7;
        int k = rem & 127;
        const float* W = (w == 0) ? W0 : (w == 1) ? W1 : W2;
        WT[(size_t)w * HD * HD + n * HD + k] = f2b(W[k * HD + n]);
    }
    if (idx < N_NODES) degc[idx] = 0;
    if (idx < NGRAPH * HD) sums[idx] = 0.f;
    if (idx < NGRAPH) cnt[idx] = 0.f;
}

// ---------------- XCD-partitioned CSR build (proven round 4) ----------------
__global__ __launch_bounds__(256) void fillx_k(const int* __restrict__ src,
                                               const int* __restrict__ dst,
                                               int* __restrict__ degc,
                                               unsigned short* __restrict__ slots) {
    const int p = blockIdx.x & 7;
    const int c = blockIdx.x >> 3;
    const int e0 = c * EPB;
    int e1 = e0 + EPB; if (e1 > N_EDGES) e1 = N_EDGES;
    for (int e = e0 + threadIdx.x; e < e1; e += 256) {
        int d = dst[e];
        if (((d >> 4) & 7) == p) {
            int s = src[e];
            int pos = atomicAdd(&degc[d], 1);
            if (pos < SLOTS)
                slots[(size_t)d * SLOTS + pos] = (unsigned short)s;
        }
    }
}

// ---------------- layer-0 MFMA matmul (fp32 in, bf16 out, *dinv epilogue) ----------------
__global__ __launch_bounds__(256) void mm_f32in_k(const float* __restrict__ X,
                                                  const unsigned short* __restrict__ WT,
                                                  const int* __restrict__ degc,
                                                  unsigned short* __restrict__ Y) {
    const int lane = threadIdx.x & 63;
    const int wave = threadIdx.x >> 6;
    const int r = lane & 15;
    const int q = lane >> 4;
    const int row0 = blockIdx.x * 64 + wave * 16;
    int arow = row0 + r; if (arow >= N_NODES) arow = N_NODES - 1;

    f4_t acc[8];
#pragma unroll
    for (int n = 0; n < 8; ++n) acc[n] = (f4_t){0.f, 0.f, 0.f, 0.f};

#pragma unroll
    for (int kb = 0; kb < 4; ++kb) {
        f4_t fa = __builtin_nontemporal_load((const f4_t*)(X + (size_t)arow * HD + kb * 32 + q * 8));
        f4_t fb = __builtin_nontemporal_load((const f4_t*)(X + (size_t)arow * HD + kb * 32 + q * 8 + 4));
        bf8_t a;
        a[0] = (short)f2b(fa[0]); a[1] = (short)f2b(fa[1]);
        a[2] = (short)f2b(fa[2]); a[3] = (short)f2b(fa[3]);
        a[4] = (short)f2b(fb[0]); a[5] = (short)f2b(fb[1]);
        a[6] = (short)f2b(fb[2]); a[7] = (short)f2b(fb[3]);
#pragma unroll
        for (int n = 0; n < 8; ++n) {
            bf8_t b = *(const bf8_t*)(WT + (size_t)(n * 16 + r) * HD + kb * 32 + q * 8);
            acc[n] = __builtin_amdgcn_mfma_f32_16x16x32_bf16(a, b, acc[n], 0, 0, 0);
        }
    }
    const int orow = row0 + q * 4;
#pragma unroll
    for (int i = 0; i < 4; ++i) {
        int rr = orow + i;
        if (rr < N_NODES) {
            float dv = rsqrtf((float)degc[rr] + 1.0f);
#pragma unroll
            for (int n = 0; n < 8; ++n)
                Y[(size_t)rr * HD + n * 16 + r] = f2b(acc[n][i] * dv);
        }
    }
}

// ---------------- fused gather+mm (input pre-scaled by dinv; relu; *dinv epilogue) ----------------
__global__ __launch_bounds__(256) void fusedGM2_k(const unsigned short* __restrict__ T,
                                                  const int* __restrict__ degc,
                                                  const unsigned short* __restrict__ slots,
                                                  const float* __restrict__ bias,
                                                  const unsigned short* __restrict__ WT,
                                                  unsigned short* __restrict__ Y) {
    __shared__ unsigned short hs[16][136];
    const int tid = threadIdx.x;
    const int base = blockIdx.x * 16;

    // ---- gather phase: one node per 16-lane group ----
    {
        const int g = tid >> 4;
        const int l = tid & 15;
        const int j8 = l * 8;
        const int i = base + g;
        const int dg = degc[i];
        int dc = dg; if (dc > SLOTS) dc = SLOTS;
        const float di = rsqrtf((float)dg + 1.0f);
        const unsigned short* sl = slots + (size_t)i * SLOTS;

        f2_t a2[4];
#pragma unroll
        for (int p = 0; p < 4; ++p) a2[p] = (f2_t){0.f, 0.f};
        int e = 0;
        for (; e + 15 < dc; e += 16) {
            us8 i0 = *(const us8*)(sl + e);
            us8 i1 = *(const us8*)(sl + e + 8);
            us8 v[16];
#pragma unroll
            for (int u = 0; u < 8; ++u) v[u]     = *(const us8*)(T + (size_t)i0[u] * HD + j8);
#pragma unroll
            for (int u = 0; u < 8; ++u) v[u + 8] = *(const us8*)(T + (size_t)i1[u] * HD + j8);
#pragma unroll
            for (int u = 0; u < 16; ++u) acc_row(a2, v[u]);
        }
        if (e < dc) {   // masked 16-chunk: vector index loads, raw[0] as safe clamp
            us8 i0 = *(const us8*)(sl + e);
            us8 i1 = *(const us8*)(sl + e + 8);
            const unsigned short safe = i0[0];
            int s[16]; float m[16];
#pragma unroll
            for (int u = 0; u < 8; ++u) {
                m[u] = (e + u < dc) ? 1.f : 0.f;
                s[u] = (e + u < dc) ? i0[u] : safe;
            }
#pragma unroll
            for (int u = 0; u < 8; ++u) {
                m[u + 8] = (e + 8 + u < dc) ? 1.f : 0.f;
                s[u + 8] = (e + 8 + u < dc) ? i1[u] : safe;
            }
            us8 v[16];
#pragma unroll
            for (int u = 0; u < 16; ++u) v[u] = *(const us8*)(T + (size_t)s[u] * HD + j8);
#pragma unroll
            for (int u = 0; u < 16; ++u) acc_row_m(a2, v[u], m[u]);
        }
        float a[8];
#pragma unroll
        for (int p = 0; p < 4; ++p) { a[2 * p] = a2[p].x; a[2 * p + 1] = a2[p].y; }
        us8 tv = *(const us8*)(T + (size_t)i * HD + j8);
        float4 bv0 = *(const float4*)(bias + j8);
        float4 bv1 = *(const float4*)(bias + j8 + 4);
        float bb[8] = {bv0.x, bv0.y, bv0.z, bv0.w, bv1.x, bv1.y, bv1.z, bv1.w};
        us8 o;
#pragma unroll
        for (int k = 0; k < 8; ++k) {
            float r = di * (a[k] + b2f(tv[k])) + bb[k];
            r = fmaxf(r, 0.f);                       // fused layers always relu
            o[k] = f2b(r);
        }
        *(us8*)(&hs[g][j8]) = o;
    }
    __syncthreads();

    // ---- MFMA phase: 16 rows x 128 cols, wave w -> col-blocks 2w, 2w+1 ----
    {
        const int lane = tid & 63;
        const int wave = tid >> 6;
        const int r = lane & 15;
        const int q = lane >> 4;
        const int n0 = wave * 2;

        f4_t acc0 = (f4_t){0.f, 0.f, 0.f, 0.f};
        f4_t acc1 = (f4_t){0.f, 0.f, 0.f, 0.f};
#pragma unroll
        for (int kb = 0; kb < 4; ++kb) {
            bf8_t a = *(const bf8_t*)(&hs[r][kb * 32 + q * 8]);
            bf8_t b0 = *(const bf8_t*)(WT + (size_t)(n0 * 16 + r) * HD + kb * 32 + q * 8);
            bf8_t b1 = *(const bf8_t*)(WT + (size_t)(n0 * 16 + 16 + r) * HD + kb * 32 + q * 8);
            acc0 = __builtin_amdgcn_mfma_f32_16x16x32_bf16(a, b0, acc0, 0, 0, 0);
            acc1 = __builtin_amdgcn_mfma_f32_16x16x32_bf16(a, b1, acc1, 0, 0, 0);
        }
#pragma unroll
        for (int i = 0; i < 4; ++i) {
            int rr = base + q * 4 + i;
            float dv = rsqrtf((float)degc[rr] + 1.0f);
            Y[(size_t)rr * HD + n0 * 16 + r]      = f2b(acc0[i] * dv);
            Y[(size_t)rr * HD + n0 * 16 + 16 + r] = f2b(acc1[i] * dv);
        }
    }
}

// ---------------- gather (layer 3, no relu) ----------------
__global__ __launch_bounds__(256) void gather_k(const unsigned short* __restrict__ T,
                                                const int* __restrict__ degc,
                                                const unsigned short* __restrict__ slots,
                                                const float* __restrict__ b,
                                                unsigned short* __restrict__ out) {
    int i = blockIdx.x * 16 + (threadIdx.x >> 4);
    if (i >= N_NODES) return;
    const int j8 = (threadIdx.x & 15) * 8;
    const int dg = degc[i];
    int dc = dg; if (dc > SLOTS) dc = SLOTS;
    const float di = rsqrtf((float)dg + 1.0f);
    const unsigned short* sl = slots + (size_t)i * SLOTS;

    f2_t a2[4];
#pragma unroll
    for (int p = 0; p < 4; ++p) a2[p] = (f2_t){0.f, 0.f};
    int e = 0;
    for (; e + 15 < dc; e += 16) {
        us8 i0 = *(const us8*)(sl + e);
        us8 i1 = *(const us8*)(sl + e + 8);
        us8 v[16];
#pragma unroll
        for (int u = 0; u < 8; ++u) v[u]     = *(const us8*)(T + (size_t)i0[u] * HD + j8);
#pragma unroll
        for (int u = 0; u < 8; ++u) v[u + 8] = *(const us8*)(T + (size_t)i1[u] * HD + j8);
#pragma unroll
        for (int u = 0; u < 16; ++u) acc_row(a2, v[u]);
    }
    if (e < dc) {
        us8 i0 = *(const us8*)(sl + e);
        us8 i1 = *(const us8*)(sl + e + 8);
        const unsigned short safe = i0[0];
        int s[16]; float m[16];
#pragma unroll
        for (int u = 0; u < 8; ++u) {
            m[u] = (e + u < dc) ? 1.f : 0.f;
            s[u] = (e + u < dc) ? i0[u] : safe;
        }
#pragma unroll
        for (int u = 0; u < 8; ++u) {
            m[u + 8] = (e + 8 + u < dc) ? 1.f : 0.f;
            s[u + 8] = (e + 8 + u < dc) ? i1[u] : safe;
        }
        us8 v[16];
#pragma unroll
        for (int u = 0; u < 16; ++u) v[u] = *(const us8*)(T + (size_t)s[u] * HD + j8);
#pragma unroll
        for (int u = 0; u < 16; ++u) acc_row_m(a2, v[u], m[u]);
    }
    float a[8];
#pragma unroll
    for (int p = 0; p < 4; ++p) { a[2 * p] = a2[p].x; a[2 * p + 1] = a2[p].y; }
    us8 tv = *(const us8*)(T + (size_t)i * HD + j8);
    float4 bv0 = *(const float4*)(b + j8);
    float4 bv1 = *(const float4*)(b + j8 + 4);
    float bb[8] = {bv0.x, bv0.y, bv0.z, bv0.w, bv1.x, bv1.y, bv1.z, bv1.w};
    us8 o;
#pragma unroll
    for (int k = 0; k < 8; ++k)
        o[k] = f2b(di * (a[k] + b2f(tv[k])) + bb[k]);
    *(us8*)(out + (size_t)i * HD + j8) = o;
}

// ---------------- vectorized global mean pool (sorted batch, proven round 7) ----------------
__global__ __launch_bounds__(256) void pool3_k(const unsigned short* __restrict__ H2,
                                               const int* __restrict__ batch,
                                               float* __restrict__ sums,
                                               float* __restrict__ cnt) {
    __shared__ float red[16][129];
    const int tid = threadIdx.x;
    const int grp = tid >> 4;
    const int cl = tid & 15;
    const int base = blockIdx.x * 128;
    const int lim = N_NODES - base;              // >0
    const int r0 = base + grp * 8;

    const int last = (lim >= 128) ? 127 : (lim - 1);
    const int bFirst = batch[base];
    const int bLast = batch[base + last];

    if (bFirst == bLast) {
        // ---- fast path: whole window one graph ----
        f2_t a2[4];
#pragma unroll
        for (int p = 0; p < 4; ++p) a2[p] = (f2_t){0.f, 0.f};
#pragma unroll
        for (int r = 0; r < 8; ++r) {
            int row = r0 + r;
            if (row < N_NODES) {
                us8 v = *(const us8*)(H2 + (size_t)row * HD + cl * 8);
                acc_row(a2, v);
            }
        }
#pragma unroll
        for (int p = 0; p < 4; ++p) {
            red[grp][cl * 8 + 2 * p]     = a2[p].x;
            red[grp][cl * 8 + 2 * p + 1] = a2[p].y;
        }
        __syncthreads();
        if (tid < 128) {
            float s = 0.f;
#pragma unroll
            for (int g = 0; g < 16; ++g) s += red[g][tid];
            atomicAdd(&sums[bFirst * HD + tid], s);
        }
        if (tid == 0) atomicAdd(&cnt[bFirst], (float)(last + 1));
    } else {
        // ---- slow path: run flush per 8-row group ----
        if (r0 < N_NODES) {
            float a[8];
#pragma unroll
            for (int k = 0; k < 8; ++k) a[k] = 0.f;
            int cur = batch[r0];
            float c = 0.f;
            for (int r = 0; r < 8; ++r) {
                int row = r0 + r;
                if (row >= N_NODES) break;
                int g = batch[row];
                if (g != cur) {
#pragma unroll
                    for (int k = 0; k < 8; ++k)
                        atomicAdd(&sums[cur * HD + cl * 8 + k], a[k]);
                    if (cl == 0) atomicAdd(&cnt[cur], c);
#pragma unroll
                    for (int k = 0; k < 8; ++k) a[k] = 0.f;
                    c = 0.f; cur = g;
                }
                us8 v = *(const us8*)(H2 + (size_t)row * HD + cl * 8);
#pragma unroll
                for (int k = 0; k < 8; ++k) a[k] += b2f(v[k]);
                c += 1.f;
            }
#pragma unroll
            for (int k = 0; k < 8; ++k)
                atomicAdd(&sums[cur * HD + cl * 8 + k], a[k]);
            if (cl == 0) atomicAdd(&cnt[cur], c);
        }
    }
}

// ---------------- head (fp32) ----------------
__global__ __launch_bounds__(512) void head_k(const float* __restrict__ sums,
                                              const float* __restrict__ cnt,
                                              const float* __restrict__ Wh,
                                              const float* __restrict__ bh,
                                              float* __restrict__ out) {
    int t = threadIdx.x;
    int g = t >> 3, o = t & 7;
    float inv = 1.0f / fmaxf(cnt[g], 1.0f);
    float acc = bh[o];
    for (int h = 0; h < HD; ++h)
        acc += sums[g * HD + h] * inv * Wh[h * NOUT + o];
    out[g * NOUT + o] = acc;
}

extern "C" void kernel_launch(void* const* d_in, const int* in_sizes, int n_in,
                              void* d_out, int out_size, void* d_ws, size_t ws_size,
                              hipStream_t stream) {
    const float* x  = (const float*)d_in[0];
    const int*   ei = (const int*)d_in[1];
    const int*   batch = (const int*)d_in[2];
    const float* W0 = (const float*)d_in[3];
    const float* b0 = (const float*)d_in[4];
    const float* W1 = (const float*)d_in[5];
    const float* b1 = (const float*)d_in[6];
    const float* W2 = (const float*)d_in[7];
    const float* b2 = (const float*)d_in[8];
    const float* Wh = (const float*)d_in[9];
    const float* bh = (const float*)d_in[10];
    float* out = (float*)d_out;

    const int* src = ei;
    const int* dst = ei + N_EDGES;

    char* wsb = (char*)d_ws;
    int*            degc  = (int*)(wsb + 0);                     // N ints (200 KB)
    unsigned short* slots = (unsigned short*)(wsb + 200000);     // N*64 ushort (6.4 MB)
    unsigned short* WT    = (unsigned short*)(wsb + 6600000);    // 3*HD*HD bf16 (98 KB)
    unsigned short* A     = (unsigned short*)(wsb + 6698304);    // N*HD bf16 (12.8 MB)
    unsigned short* C     = (unsigned short*)(wsb + 19498304);   // N*HD bf16 (12.8 MB)
    float*          sums  = (float*)(wsb + 32298304);            // G*HD fp32
    float*          cnt   = (float*)(wsb + 32331072);            // G fp32

    const int mmGrid    = (N_NODES + 63) / 64;                   // 782
    const int fillxGrid = ((N_EDGES + EPB - 1) / EPB) * 8;       // 391*8 = 3128

    // ---- weight convert + zero-init ----
    cvtw_k<<<(N_NODES + 255) / 256, 256, 0, stream>>>(W0, W1, W2, WT, degc, sums, cnt);

    // ---- XCD-partitioned CSR build ----
    fillx_k<<<fillxGrid, 256, 0, stream>>>(src, dst, degc, slots);

    // ---- layer 0 matmul: x @ W0, *dinv -> A (=T1) ----
    mm_f32in_k<<<mmGrid, 256, 0, stream>>>(x, WT, degc, A);

    // ---- layer 1: gather(T1)+b0+relu -> @W1 -> *dinv -> C (=T2) ----
    fusedGM2_k<<<GAGRID, 256, 0, stream>>>(A, degc, slots, b0, WT + HD * HD, C);

    // ---- layer 2: gather(T2)+b1+relu -> @W2 -> *dinv -> A (=T3) ----
    fusedGM2_k<<<GAGRID, 256, 0, stream>>>(C, degc, slots, b1, WT + 2 * HD * HD, A);

    // ---- layer 3 gather (no relu): -> C (=h3) ----
    gather_k<<<GAGRID, 256, 0, stream>>>(A, degc, slots, b2, C);

    // ---- vectorized pool + head ----
    pool3_k<<<(N_NODES + 127) / 128, 256, 0, stream>>>(C, batch, sums, cnt);
    head_k<<<1, 512, 0, stream>>>(sums, cnt, Wh, bh, out);
}